// Round 4
// baseline (448.415 us; speedup 1.0000x reference)
//
#include <hip/hip_runtime.h>

#define KW 11
#define PAD 5
#define TW 32
#define TH 32
#define IW 42              // TW + KW - 1
#define IH 42
#define SROW 89            // s12 row stride (floats), ODD: x1 at +0..41, x2 at +44..85
#define X2OFF 44           // read2-pairable delta (<=255 dwords)
#define HROW 165           // h row stride = 5 planes x 33, ODD
#define HP1 33             // plane offsets: h1=0, h2=33, h11=66, h22=99, h12=132
#define IMH 512
#define IMW 512

__global__ __launch_bounds__(256, 3) void ssim_main(
    const float* __restrict__ img1, const float* __restrict__ img2,
    const float* __restrict__ window, double* __restrict__ acc,
    unsigned* __restrict__ counter, float* __restrict__ out,
    unsigned nblocks, double inv_n)
{
    __shared__ float s12[IH * SROW];     // 14.9 KB
    __shared__ float hh[IH * HROW];      // 27.7 KB
    __shared__ float g[KW];
    __shared__ float wsum[4];

    const int t = threadIdx.x;

    // Separable 1D Gaussian = row-sums of the 2D window (columns sum to 1).
    if (t < KW) {
        float s = 0.f;
        for (int j = 0; j < KW; ++j) s += window[(t * KW + j) * 3];
        g[t] = s;
    }

    const int plane = blockIdx.z;
    const size_t base = (size_t)plane * IMH * IMW;
    const int ix0 = blockIdx.x * TW - PAD;
    const int iy0 = blockIdx.y * TH - PAD;

    // ---- Phase 0: stage inputs zero-padded; (x1,x2) write2-pairable (delta 44).
    for (int idx = t; idx < IH * IW; idx += 256) {
        int r = idx / IW, c = idx - r * IW;
        int gr = iy0 + r, gc = ix0 + c;
        float v1 = 0.f, v2 = 0.f;
        if (gr >= 0 && gr < IMH && gc >= 0 && gc < IMW) {
            size_t o = base + (size_t)gr * IMW + gc;
            v1 = img1[o];
            v2 = img2[o];
        }
        s12[r * SROW + c] = v1;
        s12[r * SROW + X2OFF + c] = v2;
    }
    __syncthreads();

    float wg[KW];
#pragma unroll
    for (int j = 0; j < KW; ++j) wg[j] = g[j];   // broadcast: conflict-free

    // ---- Phase 1: horizontal 11-tap; 672 tasks of 2 adjacent h-points.
    // Wave map: r = task>>4 (row), p = task&15 (col pair) -> banks: every bank
    // exactly 2 lanes per tap (odd row stride 89).  All LDS ops b32/read2.
    for (int task = t; task < IH * 16; task += 256) {
        const int r = task >> 4, p = task & 15;
        const float* srow = &s12[r * SROW + 2 * p];
        float x1[12], x2[12];
#pragma unroll
        for (int j = 0; j < 12; ++j) {           // read2-pairable (delta 44)
            x1[j] = srow[j];
            x2[j] = srow[X2OFF + j];
        }
        float q11[12], q22[12], q12[12];
#pragma unroll
        for (int j = 0; j < 12; ++j) {
            q11[j] = x1[j] * x1[j];
            q22[j] = x2[j] * x2[j];
            q12[j] = x1[j] * x2[j];
        }
        float m1a = 0.f, m2a = 0.f, a11 = 0.f, a22 = 0.f, a12 = 0.f;
        float m1b = 0.f, m2b = 0.f, b11 = 0.f, b22 = 0.f, b12 = 0.f;
#pragma unroll
        for (int j = 0; j < KW; ++j) {
            float w = wg[j];
            m1a += w * x1[j];     m1b += w * x1[j + 1];
            m2a += w * x2[j];     m2b += w * x2[j + 1];
            a11 += w * q11[j];    b11 += w * q11[j + 1];
            a22 += w * q22[j];    b22 += w * q22[j + 1];
            a12 += w * q12[j];    b12 += w * q12[j + 1];
        }
        const int ho = r * HROW + 2 * p;
        hh[ho]           = m1a;  hh[ho + 1]           = m1b;   // write2 delta 1
        hh[ho + HP1]     = m2a;  hh[ho + HP1 + 1]     = m2b;
        hh[ho + 2*HP1]   = a11;  hh[ho + 2*HP1 + 1]   = b11;
        hh[ho + 3*HP1]   = a22;  hh[ho + 3*HP1 + 1]   = b22;
        hh[ho + 4*HP1]   = a12;  hh[ho + 4*HP1 + 1]   = b12;
    }
    __syncthreads();

    // ---- Phase 2: vertical 11-tap; 256 tasks of 4 consecutive-row outputs.
    // col = t&31 stride-1 across lanes, odd row stride 165 -> <=2-way banks.
    // 14 rows x 5 values shared across 4 outputs: 70 reads / 4 outputs.
    const float C1v = 0.0001f;
    const float C2v = 0.0009f;
    const int col = t & 31;
    const int rg = t >> 5;                       // output rows rg*4 .. rg*4+3
    float am1[4] = {0,0,0,0}, am2[4] = {0,0,0,0};
    float s11[4] = {0,0,0,0}, s22[4] = {0,0,0,0}, sx[4] = {0,0,0,0};
    const float* hp = &hh[(rg * 4) * HROW + col];
#pragma unroll
    for (int i = 0; i < 14; ++i) {
        float v1  = hp[i * HROW];                // read2 pairs (0,33),(66,99)
        float v2  = hp[i * HROW + HP1];
        float w11 = hp[i * HROW + 2 * HP1];
        float w22 = hp[i * HROW + 3 * HP1];
        float w12 = hp[i * HROW + 4 * HP1];
#pragma unroll
        for (int k = 0; k < 4; ++k) {
            const int j = i - k;
            if (j >= 0 && j < KW) {
                float w = wg[j];
                am1[k] += w * v1;
                am2[k] += w * v2;
                s11[k] += w * w11;
                s22[k] += w * w22;
                sx[k]  += w * w12;
            }
        }
    }
    float lsum = 0.f;
#pragma unroll
    for (int k = 0; k < 4; ++k) {
        float mu1 = am1[k], mu2 = am2[k];
        float mu1sq = mu1 * mu1, mu2sq = mu2 * mu2, mu12 = mu1 * mu2;
        float sig1 = s11[k] - mu1sq;
        float sig2 = s22[k] - mu2sq;
        float sig12 = sx[k] - mu12;
        float num = (2.f * mu12 + C1v) * (2.f * sig12 + C2v);
        float den = (mu1sq + mu2sq + C1v) * (sig1 + sig2 + C2v);
        float r = __builtin_amdgcn_rcpf(den);
        r = r * (2.f - den * r);                 // Newton -> ~fp32 exact
        lsum += num * r;
    }

    // ---- Reduction: wave shuffle -> cross-wave LDS -> device atomic.
#pragma unroll
    for (int off = 32; off > 0; off >>= 1) lsum += __shfl_down(lsum, off, 64);
    if ((t & 63) == 0) wsum[t >> 6] = lsum;
    __syncthreads();
    if (t == 0) {
        float b = wsum[0] + wsum[1] + wsum[2] + wsum[3];
        atomicAdd(acc, (double)b);
        __threadfence();
        unsigned old = atomicAdd(counter, 1u);
        if (old == nblocks - 1) {
            double s = atomicAdd(acc, 0.0);      // coherent read of final sum
            out[0] = (float)(s * inv_n);
        }
    }
}

extern "C" void kernel_launch(void* const* d_in, const int* in_sizes, int n_in,
                              void* d_out, int out_size, void* d_ws, size_t ws_size,
                              hipStream_t stream) {
    const float* img1   = (const float*)d_in[0];
    const float* img2   = (const float*)d_in[1];
    const float* window = (const float*)d_in[2];
    float* out = (float*)d_out;
    double* acc = (double*)d_ws;
    unsigned* counter = (unsigned*)((char*)d_ws + 8);

    const int nplanes = in_sizes[0] / (IMH * IMW);   // 48
    const long long total = (long long)in_sizes[0];
    const unsigned nblocks = (IMW / TW) * (IMH / TH) * nplanes;

    hipMemsetAsync(d_ws, 0, 16, stream);
    dim3 grid(IMW / TW, IMH / TH, nplanes);
    ssim_main<<<grid, 256, 0, stream>>>(img1, img2, window, acc, counter, out,
                                        nblocks, 1.0 / (double)total);
}

// Round 5
// 446.015 us; speedup vs baseline: 1.0054x; 1.0054x over previous
//
#include <hip/hip_runtime.h>

#define KW 11
#define PAD 5
#define TW 32
#define TH 32
#define IW 42              // TW + KW - 1
#define IH 42
#define SROW 89            // s12 row stride (floats), ODD -> <=2-way banks
#define X2OFF 44           // x2 plane offset inside a row (read2-pairable delta)
#define HROW 165           // h row stride = 5 planes x 33, ODD
#define HP1 33             // plane offsets: h1=0, h2=33, h11=66, h22=99, h12=132
#define IMH 512
#define IMW 512

__global__ __launch_bounds__(256, 3) void ssim_main(
    const float* __restrict__ img1, const float* __restrict__ img2,
    const float* __restrict__ window, double* __restrict__ acc,
    unsigned* __restrict__ counter, float* __restrict__ out,
    unsigned nblocks, double inv_n)
{
    __shared__ float s12[IH * SROW];     // 14.9 KB
    __shared__ float hh[IH * HROW];      // 27.7 KB
    __shared__ float g[KW];
    __shared__ float wsum[4];

    const int t = threadIdx.x;

    // Separable 1D Gaussian = row-sums of the 2D window (columns sum to 1).
    if (t < KW) {
        float s = 0.f;
        for (int j = 0; j < KW; ++j) s += window[(t * KW + j) * 3];
        g[t] = s;
    }

    const int plane = blockIdx.z;
    const size_t base = (size_t)plane * IMH * IMW;
    const int ix0 = blockIdx.x * TW - PAD;
    const int iy0 = blockIdx.y * TH - PAD;

    // ---- Phase 0: stage inputs zero-padded (b32 writes, near-stride-1).
    for (int idx = t; idx < IH * IW; idx += 256) {
        int r = idx / IW, c = idx - r * IW;
        int gr = iy0 + r, gc = ix0 + c;
        float v1 = 0.f, v2 = 0.f;
        if (gr >= 0 && gr < IMH && gc >= 0 && gc < IMW) {
            size_t o = base + (size_t)gr * IMW + gc;
            v1 = img1[o];
            v2 = img2[o];
        }
        s12[r * SROW + c] = v1;
        s12[r * SROW + X2OFF + c] = v2;
    }
    __syncthreads();

    float wg[KW];
#pragma unroll
    for (int j = 0; j < KW; ++j) wg[j] = g[j];   // broadcast: conflict-free

    // ---- Phase 1: horizontal 11-tap; 672 tasks of 2 adjacent h-points.
    // STREAMING: each (x1,x2) pair is read once and consumed immediately —
    // live set ~30 scalars, NO local arrays (R2/R3/R4 spilled to scratch).
    for (int task = t; task < IH * 16; task += 256) {
        const int r = task >> 4, p = task & 15;
        const float* srow = &s12[r * SROW + 2 * p];
        float m1a = 0.f, m2a = 0.f, a11 = 0.f, a22 = 0.f, a12 = 0.f;
        float m1b = 0.f, m2b = 0.f, b11 = 0.f, b22 = 0.f, b12 = 0.f;
#pragma unroll
        for (int j = 0; j < 12; ++j) {
            float x1 = srow[j];
            float x2 = srow[X2OFF + j];
            float s11 = x1 * x1;
            float s22 = x2 * x2;
            float sxy = x1 * x2;
            if (j < KW) {                         // tap j for point a (col 2p)
                float w = wg[j];
                m1a += w * x1;  m2a += w * x2;
                a11 += w * s11; a22 += w * s22; a12 += w * sxy;
            }
            if (j >= 1) {                         // tap j-1 for point b (col 2p+1)
                float w = wg[j - 1];
                m1b += w * x1;  m2b += w * x2;
                b11 += w * s11; b22 += w * s22; b12 += w * sxy;
            }
        }
        const int ho = r * HROW + 2 * p;
        hh[ho]             = m1a;  hh[ho + 1]           = m1b;
        hh[ho + HP1]       = m2a;  hh[ho + HP1 + 1]     = m2b;
        hh[ho + 2 * HP1]   = a11;  hh[ho + 2 * HP1 + 1] = b11;
        hh[ho + 3 * HP1]   = a22;  hh[ho + 3 * HP1 + 1] = b22;
        hh[ho + 4 * HP1]   = a12;  hh[ho + 4 * HP1 + 1] = b12;
    }
    __syncthreads();

    // ---- Phase 2: vertical 11-tap; 256 tasks of 4 consecutive-row outputs.
    // 14 rows x 5 values shared across 4 outputs: 17.5 reads/output.
    // Live set: 20 accumulators (small fixed arrays, fully unrolled) + 5 temps.
    const float C1v = 0.0001f;
    const float C2v = 0.0009f;
    const int col = t & 31;
    const int rg = t >> 5;                        // output rows rg*4 .. rg*4+3
    float am1[4] = {0, 0, 0, 0}, am2[4] = {0, 0, 0, 0};
    float s11a[4] = {0, 0, 0, 0}, s22a[4] = {0, 0, 0, 0}, sxa[4] = {0, 0, 0, 0};
    const float* hp = &hh[(rg * 4) * HROW + col];
#pragma unroll
    for (int i = 0; i < 14; ++i) {
        float v1  = hp[i * HROW];
        float v2  = hp[i * HROW + HP1];
        float w11 = hp[i * HROW + 2 * HP1];
        float w22 = hp[i * HROW + 3 * HP1];
        float w12 = hp[i * HROW + 4 * HP1];
#pragma unroll
        for (int k = 0; k < 4; ++k) {
            const int j = i - k;
            if (j >= 0 && j < KW) {
                float w = wg[j];
                am1[k]  += w * v1;
                am2[k]  += w * v2;
                s11a[k] += w * w11;
                s22a[k] += w * w22;
                sxa[k]  += w * w12;
            }
        }
    }
    float lsum = 0.f;
#pragma unroll
    for (int k = 0; k < 4; ++k) {
        float mu1 = am1[k], mu2 = am2[k];
        float mu1sq = mu1 * mu1, mu2sq = mu2 * mu2, mu12 = mu1 * mu2;
        float sig1 = s11a[k] - mu1sq;
        float sig2 = s22a[k] - mu2sq;
        float sig12 = sxa[k] - mu12;
        float num = (2.f * mu12 + C1v) * (2.f * sig12 + C2v);
        float den = (mu1sq + mu2sq + C1v) * (sig1 + sig2 + C2v);
        float r = __builtin_amdgcn_rcpf(den);
        r = r * (2.f - den * r);                  // Newton -> ~fp32 exact
        lsum += num * r;
    }

    // ---- Reduction: wave shuffle -> cross-wave LDS -> device atomic.
#pragma unroll
    for (int off = 32; off > 0; off >>= 1) lsum += __shfl_down(lsum, off, 64);
    if ((t & 63) == 0) wsum[t >> 6] = lsum;
    __syncthreads();
    if (t == 0) {
        float b = wsum[0] + wsum[1] + wsum[2] + wsum[3];
        atomicAdd(acc, (double)b);
        __threadfence();
        unsigned old = atomicAdd(counter, 1u);
        if (old == nblocks - 1) {
            double s = atomicAdd(acc, 0.0);       // coherent read of final sum
            out[0] = (float)(s * inv_n);
        }
    }
}

extern "C" void kernel_launch(void* const* d_in, const int* in_sizes, int n_in,
                              void* d_out, int out_size, void* d_ws, size_t ws_size,
                              hipStream_t stream) {
    const float* img1   = (const float*)d_in[0];
    const float* img2   = (const float*)d_in[1];
    const float* window = (const float*)d_in[2];
    float* out = (float*)d_out;
    double* acc = (double*)d_ws;
    unsigned* counter = (unsigned*)((char*)d_ws + 8);

    const int nplanes = in_sizes[0] / (IMH * IMW);   // 48
    const long long total = (long long)in_sizes[0];
    const unsigned nblocks = (IMW / TW) * (IMH / TH) * nplanes;

    hipMemsetAsync(d_ws, 0, 16, stream);
    dim3 grid(IMW / TW, IMH / TH, nplanes);
    ssim_main<<<grid, 256, 0, stream>>>(img1, img2, window, acc, counter, out,
                                        nblocks, 1.0 / (double)total);
}

// Round 6
// 219.151 us; speedup vs baseline: 2.0461x; 2.0352x over previous
//
#include <hip/hip_runtime.h>

#define KW 11
#define PAD 5
#define TW 32
#define TH 32
#define IW 42              // TW + KW - 1
#define IH 42
#define SROW 89            // s12 row stride (floats), ODD -> <=2-way banks
#define X2OFF 44           // x2 plane offset inside a row
#define HROW 165           // h row stride = 5 planes x 33, ODD
#define HP1 33             // plane offsets: h1=0, h2=33, h11=66, h22=99, h12=132
#define IMH 512
#define IMW 512
#define NBLK 12288         // 16 x 16 x 48

__global__ __launch_bounds__(256, 3) void ssim_main(
    const float* __restrict__ img1, const float* __restrict__ img2,
    const float* __restrict__ window, float* __restrict__ partial)
{
    __shared__ float s12[IH * SROW];     // 14.9 KB
    __shared__ float hh[IH * HROW];      // 27.7 KB
    __shared__ float g[KW];
    __shared__ float wsum[4];

    const int t = threadIdx.x;

    // Separable 1D Gaussian = row-sums of the 2D window (columns sum to 1).
    if (t < KW) {
        float s = 0.f;
        for (int j = 0; j < KW; ++j) s += window[(t * KW + j) * 3];
        g[t] = s;
    }

    const int plane = blockIdx.z;
    const size_t base = (size_t)plane * IMH * IMW;
    const int ix0 = blockIdx.x * TW - PAD;
    const int iy0 = blockIdx.y * TH - PAD;

    // ---- Phase 0: stage inputs zero-padded (b32 writes).
    for (int idx = t; idx < IH * IW; idx += 256) {
        int r = idx / IW, c = idx - r * IW;
        int gr = iy0 + r, gc = ix0 + c;
        float v1 = 0.f, v2 = 0.f;
        if (gr >= 0 && gr < IMH && gc >= 0 && gc < IMW) {
            size_t o = base + (size_t)gr * IMW + gc;
            v1 = img1[o];
            v2 = img2[o];
        }
        s12[r * SROW + c] = v1;
        s12[r * SROW + X2OFF + c] = v2;
    }
    __syncthreads();

    float wg[KW];
#pragma unroll
    for (int j = 0; j < KW; ++j) wg[j] = g[j];   // broadcast: conflict-free

    // ---- Phase 1: horizontal 11-tap; 672 tasks of 2 adjacent h-points.
    // Streaming: each (x1,x2) read once, consumed immediately (no arrays).
    for (int task = t; task < IH * 16; task += 256) {
        const int r = task >> 4, p = task & 15;
        const float* srow = &s12[r * SROW + 2 * p];
        float m1a = 0.f, m2a = 0.f, a11 = 0.f, a22 = 0.f, a12 = 0.f;
        float m1b = 0.f, m2b = 0.f, b11 = 0.f, b22 = 0.f, b12 = 0.f;
#pragma unroll
        for (int j = 0; j < 12; ++j) {
            float x1 = srow[j];
            float x2 = srow[X2OFF + j];
            float s11 = x1 * x1;
            float s22 = x2 * x2;
            float sxy = x1 * x2;
            if (j < KW) {                         // tap j for point a (col 2p)
                float w = wg[j];
                m1a += w * x1;  m2a += w * x2;
                a11 += w * s11; a22 += w * s22; a12 += w * sxy;
            }
            if (j >= 1) {                         // tap j-1 for point b (col 2p+1)
                float w = wg[j - 1];
                m1b += w * x1;  m2b += w * x2;
                b11 += w * s11; b22 += w * s22; b12 += w * sxy;
            }
        }
        const int ho = r * HROW + 2 * p;
        hh[ho]             = m1a;  hh[ho + 1]           = m1b;
        hh[ho + HP1]       = m2a;  hh[ho + HP1 + 1]     = m2b;
        hh[ho + 2 * HP1]   = a11;  hh[ho + 2 * HP1 + 1] = b11;
        hh[ho + 3 * HP1]   = a22;  hh[ho + 3 * HP1 + 1] = b22;
        hh[ho + 4 * HP1]   = a12;  hh[ho + 4 * HP1 + 1] = b12;
    }
    __syncthreads();

    // ---- Phase 2: vertical 11-tap; 4 consecutive-row outputs per thread.
    const float C1v = 0.0001f;
    const float C2v = 0.0009f;
    const int col = t & 31;
    const int rg = t >> 5;
    float am1[4] = {0, 0, 0, 0}, am2[4] = {0, 0, 0, 0};
    float s11a[4] = {0, 0, 0, 0}, s22a[4] = {0, 0, 0, 0}, sxa[4] = {0, 0, 0, 0};
    const float* hp = &hh[(rg * 4) * HROW + col];
#pragma unroll
    for (int i = 0; i < 14; ++i) {
        float v1  = hp[i * HROW];
        float v2  = hp[i * HROW + HP1];
        float w11 = hp[i * HROW + 2 * HP1];
        float w22 = hp[i * HROW + 3 * HP1];
        float w12 = hp[i * HROW + 4 * HP1];
#pragma unroll
        for (int k = 0; k < 4; ++k) {
            const int j = i - k;
            if (j >= 0 && j < KW) {
                float w = wg[j];
                am1[k]  += w * v1;
                am2[k]  += w * v2;
                s11a[k] += w * w11;
                s22a[k] += w * w22;
                sxa[k]  += w * w12;
            }
        }
    }
    float lsum = 0.f;
#pragma unroll
    for (int k = 0; k < 4; ++k) {
        float mu1 = am1[k], mu2 = am2[k];
        float mu1sq = mu1 * mu1, mu2sq = mu2 * mu2, mu12 = mu1 * mu2;
        float sig1 = s11a[k] - mu1sq;
        float sig2 = s22a[k] - mu2sq;
        float sig12 = sxa[k] - mu12;
        float num = (2.f * mu12 + C1v) * (2.f * sig12 + C2v);
        float den = (mu1sq + mu2sq + C1v) * (sig1 + sig2 + C2v);
        float r = __builtin_amdgcn_rcpf(den);
        r = r * (2.f - den * r);                  // Newton -> ~fp32 exact
        lsum += num * r;
    }

    // ---- Reduction: wave shuffle -> cross-wave LDS -> PLAIN per-block store.
    // No atomics, no fence: 12288 same-line RMWs serialized at ~30 ns each was
    // the R2-R5 ~365 us floor (blocks held LDS while wave 0 waited on the line).
#pragma unroll
    for (int off = 32; off > 0; off >>= 1) lsum += __shfl_down(lsum, off, 64);
    if ((t & 63) == 0) wsum[t >> 6] = lsum;
    __syncthreads();
    if (t == 0) {
        unsigned bid = (blockIdx.z * gridDim.y + blockIdx.y) * gridDim.x
                     + blockIdx.x;
        partial[bid] = wsum[0] + wsum[1] + wsum[2] + wsum[3];
    }
}

__global__ __launch_bounds__(256) void ssim_reduce(
    const float* __restrict__ partial, float* __restrict__ out, double inv_n)
{
    __shared__ double dsum[4];
    const int t = threadIdx.x;
    double s = 0.0;
    for (int i = t; i < NBLK; i += 256) s += (double)partial[i];
#pragma unroll
    for (int off = 32; off > 0; off >>= 1) s += __shfl_down(s, off, 64);
    if ((t & 63) == 0) dsum[t >> 6] = s;
    __syncthreads();
    if (t == 0) out[0] = (float)((dsum[0] + dsum[1] + dsum[2] + dsum[3]) * inv_n);
}

extern "C" void kernel_launch(void* const* d_in, const int* in_sizes, int n_in,
                              void* d_out, int out_size, void* d_ws, size_t ws_size,
                              hipStream_t stream) {
    const float* img1   = (const float*)d_in[0];
    const float* img2   = (const float*)d_in[1];
    const float* window = (const float*)d_in[2];
    float* out = (float*)d_out;
    float* partial = (float*)d_ws;               // 12288 floats = 48 KB

    const int nplanes = in_sizes[0] / (IMH * IMW);   // 48
    const long long total = (long long)in_sizes[0];

    dim3 grid(IMW / TW, IMH / TH, nplanes);      // 16 x 16 x 48 = 12288
    ssim_main<<<grid, 256, 0, stream>>>(img1, img2, window, partial);
    ssim_reduce<<<1, 256, 0, stream>>>(partial, out, 1.0 / (double)total);
}